// Round 8
// baseline (62.302 us; speedup 1.0000x reference)
//
#include <hip/hip_runtime.h>
#include <cstdint>

#define NK 16384
#define NB 4096
#define NM 256
#define LOG2E 1.4426950408889634f
#define TWO_LOG2E 2.8853900817779268f

typedef __attribute__((ext_vector_type(8))) short short8;
typedef __attribute__((ext_vector_type(4))) float floatx4;

#if __has_builtin(__builtin_amdgcn_exp2f)
#define EXP2F(x) __builtin_amdgcn_exp2f(x)
#else
#define EXP2F(x) exp2f(x)
#endif

// Static device scratch: bf16 copy of x_basis [4096][256], per-center {W[n], ||c_n||^2*log2e}.
__device__ unsigned short g_xb[NB * NM];   // 2 MB (L2-resident per XCD)
__device__ float2 g_wc[NB];                // 32 KB

__device__ __forceinline__ unsigned short f2bf(float f) {
    unsigned int u = __float_as_uint(f);
    u += 0x7FFFu + ((u >> 16) & 1u);       // RTN-even
    return (unsigned short)(u >> 16);
}

// One wave per x_basis row: convert 256 fp32 -> bf16, compute ||c||^2 * log2e.
__global__ __launch_bounds__(256) void rbf_prep(const float* __restrict__ xb,
                                                const float* __restrict__ W) {
    const int row  = blockIdx.x * 4 + (threadIdx.x >> 6);
    const int lane = threadIdx.x & 63;
    const float4 v = ((const float4*)(xb + row * NM))[lane];
    float ss = v.x * v.x + v.y * v.y + v.z * v.z + v.w * v.w;
    #pragma unroll
    for (int m = 1; m < 64; m <<= 1) ss += __shfl_xor(ss, m, 64);
    ushort4 o;
    o.x = f2bf(v.x); o.y = f2bf(v.y); o.z = f2bf(v.z); o.w = f2bf(v.w);
    *(ushort4*)(g_xb + row * NM + lane * 4) = o;
    if (lane == 0) g_wc[row] = make_float2(W[row], ss * LOG2E);
}

// Stage QUARTER of one 16-center tile (this wave's 2 chunk-groups; the 4 waves of
// the slice-group cover j=0..7). LDS dest linear (uniform base + lane*16);
// bank-conflict swizzle applied on the GLOBAL source side (chunk ^= row&7);
// ds_read applies the same involution.
#define STAGE(t, bufIdx)                                                              \
    {                                                                                 \
        _Pragma("unroll")                                                             \
        for (int j2 = 0; j2 < 2; ++j2) {                                              \
            const int j  = sub * 2 + j2;       /* chunk-group 0..7, split by sub */   \
            const int q  = j * 64 + lane;      /* 16B-chunk index within tile */      \
            const int rr = q >> 5;             /* center row 0..15 */                 \
            const int cc = q & 31;             /* 16B chunk within row */             \
            const unsigned short* srcp =                                              \
                g_xb + (n0 + (t) * 16 + rr) * NM + ((cc ^ (rr & 7)) * 8);             \
            unsigned short* dstp = &Bt[gr][bufIdx][j * 512];                          \
            __builtin_amdgcn_global_load_lds(                                         \
                (const __attribute__((address_space(1))) void*)srcp,                  \
                (__attribute__((address_space(3))) void*)dstp, 16, 0, 0);             \
        }                                                                             \
    }

// ---- A prologue helpers: NAMED fragments only (no runtime-indexed arrays).
#define LOADFRAG(dst, s)                                                              \
    {                                                                                 \
        const float4 f0 = xr4[(s) * 8 + g * 2];                                       \
        const float4 f1 = xr4[(s) * 8 + g * 2 + 1];                                   \
        ss += f0.x * f0.x + f0.y * f0.y + f0.z * f0.z + f0.w * f0.w                   \
            + f1.x * f1.x + f1.y * f1.y + f1.z * f1.z + f1.w * f1.w;                  \
        short8 t;                                                                     \
        t[0] = (short)f2bf(f0.x); t[1] = (short)f2bf(f0.y);                           \
        t[2] = (short)f2bf(f0.z); t[3] = (short)f2bf(f0.w);                           \
        t[4] = (short)f2bf(f1.x); t[5] = (short)f2bf(f1.y);                           \
        t[6] = (short)f2bf(f1.z); t[7] = (short)f2bf(f1.w);                           \
        dst = t;                                                                      \
    }

// One K=32 step: 1 ds_read_b128 -> 1 MFMA into chain register cr. s literal.
#define CSTEP(s, cr)                                                                  \
    {                                                                                 \
        const short8 b =                                                              \
            *(const short8*)(bp + r * 256 + ((((s) * 4 + g) ^ (r & 7)) * 8));         \
        cr = __builtin_amdgcn_mfma_f32_16x16x32_bf16(af##s, b, cr, 0, 0, 0);          \
    }

#define EPI1(cc, xsv, acref)                                                          \
    acref = fmaf(EXP2F(fmaf(cc, TWO_LOG2E, nb - (xsv))), wgt, acref);

// One 16-center tile: 8 ds_read_b128 -> 8 MFMA (two 4-deep chains for ILP)
// -> fused exp/W epilogue (all static indices).
#define COMPUTE(bufIdx, wcv)                                                          \
    {                                                                                 \
        const unsigned short* bp = &Bt[gr][bufIdx][0];                                \
        floatx4 ca = {0.f, 0.f, 0.f, 0.f}, cb = {0.f, 0.f, 0.f, 0.f};                 \
        CSTEP(0, ca) CSTEP(1, cb) CSTEP(2, ca) CSTEP(3, cb)                           \
        CSTEP(4, ca) CSTEP(5, cb) CSTEP(6, ca) CSTEP(7, cb)                           \
        const floatx4 c = ca + cb;                                                    \
        const float nb  = -(wcv).y;                                                   \
        const float wgt = (wcv).x;                                                    \
        EPI1(c[0], xs.x, ac.x) EPI1(c[1], xs.y, ac.y)                                 \
        EPI1(c[2], xs.z, ac.z) EPI1(c[3], xs.w, ac.w)                                 \
    }

// One pipeline sub-iteration for tile t (buf/wc names are literals):
// load wc(t+2), stage tile t+2 (depth-2 ahead), drain OWN tile-t ops (vmcnt(6)
// = 2 newer rounds x 3 vmem stay in flight), raw barrier (slice-mates' quarters
// all drained by their own vmcnt before THEIR barrier), then compute tile t.
#define SUBITER(t_ahead, bufStage, bufUse, wcLoad, wcUse)                             \
    wcLoad = g_wc[n0 + ((t_ahead) & 63) * 16 + r];                                    \
    STAGE((t_ahead) & 63, bufStage);                                                  \
    asm volatile("s_waitcnt vmcnt(6)" ::: "memory");                                  \
    __builtin_amdgcn_s_barrier();                                                     \
    __builtin_amdgcn_sched_barrier(0);                                                \
    COMPUTE(bufUse, wcUse);

#define RED(val, j)                                                                   \
    {                                                                                 \
        float v = (val);                                                              \
        v += __shfl_xor(v, 1, 64); v += __shfl_xor(v, 2, 64);                         \
        v += __shfl_xor(v, 4, 64); v += __shfl_xor(v, 8, 64);                         \
        if (r == 0) rowacc[w][g * 4 + (j)] = v;                                       \
    }

// 256 blocks (1/CU), 1024 threads (16 waves = 4/SIMD: R7 showed 2 waves/SIMD in
// barrier-lockstep can't fill the matrix pipe -- MfmaUtil 24%, round time 3.4x
// matrix demand). Block owns 64 rows. Wave w: row-tile sub=w&3 (afrag 32 VGPR),
// center slice gr=w>>2 (1024 centers, 64 tiles); the 4 waves of a slice share
// one tile stream, each staging a quarter. R7's proven 4-buffer depth-2
// drain-own-then-barrier pattern, vmcnt(6).
__global__ void
__attribute__((amdgpu_flat_work_group_size(1024, 1024), amdgpu_waves_per_eu(4, 4)))
rbf_main(const float* __restrict__ x,
         const float* __restrict__ bptr,
         float* __restrict__ out) {
    __shared__ __align__(16) unsigned short Bt[4][4][16 * NM];  // [slice][buf] 128 KB
    __shared__ __align__(16) float xsl[64];
    __shared__ float rowacc[16][16];

    const int tid  = threadIdx.x;
    const int w    = tid >> 6;
    const int lane = tid & 63;
    const int r    = lane & 15;
    const int g    = lane >> 4;
    const int sub  = w & 3;            // row-tile / staging quarter
    const int gr   = w >> 2;           // slice group 0..3
    const int row0 = blockIdx.x * 64;
    const int n0   = gr * 1024;        // shared center-slice base

    short8 af0, af1, af2, af3, af4, af5, af6, af7;
    {
        const float4* xr4 = (const float4*)(x + (row0 + sub * 16 + r) * NM);
        float ss = 0.f;
        LOADFRAG(af0, 0) LOADFRAG(af1, 1) LOADFRAG(af2, 2) LOADFRAG(af3, 3)
        LOADFRAG(af4, 4) LOADFRAG(af5, 5) LOADFRAG(af6, 6) LOADFRAG(af7, 7)
        ss += __shfl_xor(ss, 16, 64);
        ss += __shfl_xor(ss, 32, 64);
        if (gr == 0 && g == 0) xsl[sub * 16 + r] = ss * LOG2E;
    }
    __syncthreads();

    // per-lane ||x||^2*log2e for this lane's C/D rows: sub*16 + g*4 + {0..3}
    const float4 xs = *(const float4*)&xsl[sub * 16 + g * 4];

    float4 ac = {0.f, 0.f, 0.f, 0.f};

    // prologue: tiles 0,1 + wc(0),wc(1) in flight (6 vmem ops outstanding)
    STAGE(0, 0);
    float2 wcA = g_wc[n0 + 0 * 16 + r];
    STAGE(1, 1);
    float2 wcB = g_wc[n0 + 1 * 16 + r];
    float2 wcC, wcD;

    #pragma unroll 1
    for (int t = 0; t < 64; t += 4) {
        SUBITER(t + 2, 2, 0, wcC, wcA)   // compute tile t
        SUBITER(t + 3, 3, 1, wcD, wcB)   // compute tile t+1
        SUBITER(t + 4, 0, 2, wcA, wcC)   // compute tile t+2
        SUBITER(t + 5, 1, 3, wcB, wcD)   // compute tile t+3
    }

    // ---- reduce over the 16 column-lanes; combine 4 slices' N-partials ----
    RED(ac.x, 0) RED(ac.y, 1) RED(ac.z, 2) RED(ac.w, 3)
    __syncthreads();

    if (tid < 64) {
        const int rt = tid >> 4;       // row-tile
        const int lr = tid & 15;       // row within tile
        float logit = bptr[0];
        #pragma unroll
        for (int s = 0; s < 4; ++s) logit += rowacc[s * 4 + rt][lr];
        out[row0 + tid] = 1.f / (1.f + EXP2F(-logit * LOG2E));
    }
}

extern "C" void kernel_launch(void* const* d_in, const int* in_sizes, int n_in,
                              void* d_out, int out_size, void* d_ws, size_t ws_size,
                              hipStream_t stream) {
    const float* x  = (const float*)d_in[0];   // [16384,256]
    const float* xb = (const float*)d_in[1];   // [4096,256]
    const float* W  = (const float*)d_in[2];   // [1,4096]
    const float* b  = (const float*)d_in[3];   // [1]
    float* out = (float*)d_out;                // [16384,1]

    rbf_prep<<<dim3(NB / 4), dim3(256), 0, stream>>>(xb, W);
    rbf_main<<<dim3(NK / 64), dim3(1024), 0, stream>>>(x, b, out);
}